// Round 2
// baseline (1322.519 us; speedup 1.0000x reference)
//
#include <hip/hip_runtime.h>
#include <math.h>

// Problem constants (B=1 fixed by reference)
#define NP 9216          // S*S spatial positions
#define DC 256           // channels
#define DN (DC * NP)

#define FEPS 2.220446049250313e-16f

// ---------------- Kernel 1: L2-normalize over channel dim ----------------
__global__ __launch_bounds__(256) void knorm(
    const float* __restrict__ X, const float* __restrict__ Y,
    float* __restrict__ Xf, float* __restrict__ Xf_out,
    float* __restrict__ Yf, float* __restrict__ YfT,
    float* __restrict__ lacc)
{
    int t = blockIdx.x * 256 + threadIdx.x;
    if (t == 0) *lacc = 0.0f;   // zero loss accumulator (d_ws is poisoned each call)

    const float* src = (t < NP) ? X : Y;
    int n = (t < NP) ? t : t - NP;

    float s = 0.0f;
    #pragma unroll 8
    for (int d = 0; d < DC; ++d) {
        float v = src[d * NP + n];
        s = fmaf(v, v, s);
    }
    float inv = 1.0f / (sqrtf(s) + FEPS);

    if (t < NP) {
        #pragma unroll 4
        for (int d = 0; d < DC; ++d) {
            float v = src[d * NP + n] * inv;
            Xf[d * NP + n] = v;
            Xf_out[d * NP + n] = v;
        }
    } else {
        #pragma unroll 4
        for (int d = 0; d < DC; ++d) {
            float v = src[d * NP + n] * inv;
            Yf[d * NP + n] = v;
            YfT[n * DC + d] = v;
        }
    }
}

// ---------------- Kernel 2: fused sim-GEMM + per-row argmax ----------------
// C[n,m] = sum_d Xf[d,n]*Yf[d,m]; running (max,idx), never materialized.
// Tile: BN=96 x BM=128, BK=16, 384 threads, 4x8 acc/thread.
// Grid: 96 n-bands x 8 m-chunks = 768 blocks = 3/CU exactly.
//
// R2 changes vs R1 (theory: exposed LDS latency + 4-way B bank conflicts):
//  - thread columns are {tx*4+j, 64+tx*4+j}: B reads span all 32 banks,
//    2-way aliasing only (free per m136). R1's tx*8 was 4-way conflicted.
//  - register double-buffer of a/b fragments: k+1 ds_reads issue before
//    k's FMAs, so lgkmcnt wait is covered by 64 cyc of independent FMAs.
//  - LDS double-buffer + register staging: global loads for kt+1 issue
//    before compute on kt; LDS writes go to the other buffer; ONE barrier
//    per kt. Global latency hidden behind ~1024 cyc of FMA.
#define BN 96
#define BM 128
#define BK 16
#define NCHUNK 8
#define MCHUNK (NP / NCHUNK)          // 1152
#define MT_PER_CHUNK (MCHUNK / BM)    // 9

__global__ __launch_bounds__(384) void ksim(
    const float* __restrict__ Xf, const float* __restrict__ Yf,
    float* __restrict__ pmax, int* __restrict__ pidx)
{
    __shared__ float As[2][BK][BN];   // 2 x 16 x 96
    __shared__ float Bs[2][BK][BM];   // 2 x 16 x 128

    const int tid = threadIdx.x;
    const int tx = tid & 15;       // 16 col-groups
    const int ty = tid >> 4;       // 24 row-groups (4 rows each)
    const int n0 = blockIdx.x * BN;
    const int chunk = blockIdx.y;
    const int mbase = chunk * MCHUNK;

    // staging index maps (one A float4/thread; B: all threads + first 128)
    const int ar = tid / 24, ac = (tid % 24) * 4;
    const int br = tid >> 5, bc = (tid & 31) * 4;
    const int br2 = (tid + 384) >> 5, bc2 = ((tid + 384) & 31) * 4;

    float best[4];
    int   bidx[4];
    #pragma unroll
    for (int i = 0; i < 4; ++i) { best[i] = -INFINITY; bidx[i] = 0; }

    for (int mt = 0; mt < MT_PER_CHUNK; ++mt) {
        const int m0 = mbase + mt * BM;
        float acc[4][8];
        #pragma unroll
        for (int i = 0; i < 4; ++i)
            #pragma unroll
            for (int j = 0; j < 8; ++j) acc[i][j] = 0.0f;

        // ---- prologue: stage kt=0 into buffer 0 ----
        float4 a_st = *(const float4*)(&Xf[ar * NP + n0 + ac]);
        float4 b_st = *(const float4*)(&Yf[br * NP + m0 + bc]);
        float4 b_st2;
        if (tid < 128)
            b_st2 = *(const float4*)(&Yf[br2 * NP + m0 + bc2]);
        *(float4*)(&As[0][ar][ac]) = a_st;
        *(float4*)(&Bs[0][br][bc]) = b_st;
        if (tid < 128) *(float4*)(&Bs[0][br2][bc2]) = b_st2;
        __syncthreads();

        int cur = 0;
        for (int kt = 0; kt < DC / BK; ++kt) {
            // issue global loads for kt+1 (consumed after compute)
            if (kt < DC / BK - 1) {
                const int kb = (kt + 1) * BK;
                a_st = *(const float4*)(&Xf[(kb + ar) * NP + n0 + ac]);
                b_st = *(const float4*)(&Yf[(kb + br) * NP + m0 + bc]);
                if (tid < 128)
                    b_st2 = *(const float4*)(&Yf[(kb + br2) * NP + m0 + bc2]);
            }

            // ---- compute on buffer `cur`, fragments register-pipelined ----
            {
                const float* Ab  = &As[cur][0][ty * 4];
                const float* Bb0 = &Bs[cur][0][tx * 4];
                const float* Bb1 = &Bs[cur][0][64 + tx * 4];
                float4 a  = *(const float4*)Ab;
                float4 b0 = *(const float4*)Bb0;
                float4 b1 = *(const float4*)Bb1;
                #pragma unroll
                for (int k = 0; k < BK; ++k) {
                    float4 an, b0n, b1n;
                    if (k < BK - 1) {
                        an  = *(const float4*)(Ab  + (k + 1) * BN);
                        b0n = *(const float4*)(Bb0 + (k + 1) * BM);
                        b1n = *(const float4*)(Bb1 + (k + 1) * BM);
                    }
                    const float av[4] = {a.x, a.y, a.z, a.w};
                    const float bv[8] = {b0.x, b0.y, b0.z, b0.w,
                                         b1.x, b1.y, b1.z, b1.w};
                    #pragma unroll
                    for (int i = 0; i < 4; ++i)
                        #pragma unroll
                        for (int j = 0; j < 8; ++j)
                            acc[i][j] = fmaf(av[i], bv[j], acc[i][j]);
                    if (k < BK - 1) { a = an; b0 = b0n; b1 = b1n; }
                }
            }

            // ---- stage kt+1 into the other buffer; single barrier ----
            if (kt < DC / BK - 1) {
                int nxt = cur ^ 1;
                *(float4*)(&As[nxt][ar][ac]) = a_st;
                *(float4*)(&Bs[nxt][br][bc]) = b_st;
                if (tid < 128) *(float4*)(&Bs[nxt][br2][bc2]) = b_st2;
                __syncthreads();
            }
            cur ^= 1;
        }

        // Fold this m-tile into the running argmax. Column order within a
        // thread is ascending (j<4 -> tx*4+j, j>=4 -> 64+tx*4+j-4); strict
        // '>' keeps the FIRST max (jnp.argmax tie semantics).
        #pragma unroll
        for (int i = 0; i < 4; ++i)
            #pragma unroll
            for (int j = 0; j < 8; ++j) {
                float v = acc[i][j];
                int col = (j < 4) ? (m0 + tx * 4 + j) : (m0 + 64 + tx * 4 + j - 4);
                if (v > best[i] || (v == best[i] && col < bidx[i])) {
                    if (v > best[i]) { best[i] = v; bidx[i] = col; }
                    else             { bidx[i] = bidx[i] < col ? bidx[i] : col; }
                }
            }
    }

    // Reduce across the 16 tx lanes (same rows). xor<16 stays in group.
    #pragma unroll
    for (int off = 1; off < 16; off <<= 1) {
        #pragma unroll
        for (int i = 0; i < 4; ++i) {
            float ov = __shfl_xor(best[i], off, 64);
            int   oi = __shfl_xor(bidx[i], off, 64);
            if (ov > best[i] || (ov == best[i] && oi < bidx[i])) {
                best[i] = ov; bidx[i] = oi;
            }
        }
    }

    if (tx == 0) {
        #pragma unroll
        for (int i = 0; i < 4; ++i) {
            int row = n0 + ty * 4 + i;
            pmax[row * NCHUNK + chunk] = best[i];
            pidx[row * NCHUNK + chunk] = bidx[i];
        }
    }
}

// ---------------- Kernel 3: reduce chunk partials -> nn_idx ----------------
__global__ __launch_bounds__(256) void kred(
    const float* __restrict__ pmax, const int* __restrict__ pidx,
    int* __restrict__ nn)
{
    int t = blockIdx.x * 256 + threadIdx.x;
    if (t >= NP) return;
    float b = -INFINITY;
    int bi = 0x7fffffff;
    #pragma unroll
    for (int c = 0; c < NCHUNK; ++c) {
        float v = pmax[t * NCHUNK + c];
        int  id = pidx[t * NCHUNK + c];
        if (v > b || (v == b && id < bi)) { b = v; bi = id; }
    }
    nn[t] = bi;
}

// ---------------- Kernel 4: gather Y_sel + fused MSE loss ----------------
__global__ __launch_bounds__(256) void kgather(
    const float* __restrict__ YfT, const int* __restrict__ nn,
    const float* __restrict__ Xf, float* __restrict__ Ysel,
    float* __restrict__ lacc)
{
    __shared__ float tile[64][65];
    __shared__ int   idxs[64];
    __shared__ float wsum[4];

    const int n0 = blockIdx.x * 64;
    const int d0 = blockIdx.y * 64;
    const int tid = threadIdx.x;

    if (tid < 64) idxs[tid] = nn[n0 + tid];
    __syncthreads();

    const int c  = tid & 63;   // lane within wave
    const int r0 = tid >> 6;   // wave id 0..3

    #pragma unroll
    for (int s = 0; s < 16; ++s) {
        int r = s * 4 + r0;    // n-row within tile; whole wave shares r
        tile[r][c] = YfT[(long)idxs[r] * DC + d0 + c];
    }
    __syncthreads();

    float lsum = 0.0f;
    #pragma unroll
    for (int s = 0; s < 16; ++s) {
        int a = s * 4 + r0;            // d-offset within tile
        int d = d0 + a;
        int n = n0 + c;
        float y = tile[c][a];          // stride-65 read: conflict-free
        float x = Xf[(long)d * NP + n];
        float diff = x - y;
        lsum = fmaf(diff, diff, lsum);
        Ysel[(long)d * NP + n] = y;    // coalesced over n
    }

    #pragma unroll
    for (int off = 32; off >= 1; off >>= 1)
        lsum += __shfl_xor(lsum, off, 64);
    if ((tid & 63) == 0) wsum[tid >> 6] = lsum;
    __syncthreads();
    if (tid == 0)
        atomicAdd(lacc, wsum[0] + wsum[1] + wsum[2] + wsum[3]);
}

// ---------------- Kernel 5: finalize loss ----------------
__global__ void kfin(const float* __restrict__ lacc, float* __restrict__ out)
{
    out[0] = lacc[0] * (1.0f / (float)DN);
}

extern "C" void kernel_launch(void* const* d_in, const int* in_sizes, int n_in,
                              void* d_out, int out_size, void* d_ws, size_t ws_size,
                              hipStream_t stream)
{
    const float* X = (const float*)d_in[0];   // X_features [1,256,96,96]
    const float* Y = (const float*)d_in[1];   // Y_features [1,256,96,96]
    // d_in[2], d_in[3] (images) are dead code in the reference — unused.

    float* out = (float*)d_out;
    float* Ysel_out = out + 1;          // output 1: Y_sel [1,D,N]
    float* Xf_out   = out + 1 + DN;     // output 2: Xf   [1,D,N]

    float* Xf   = (float*)d_ws;         // DN
    float* Yf   = Xf + DN;              // DN
    float* YfT  = Yf + DN;              // DN  ([N,D] transposed)
    float* pmax = YfT + DN;             // NP*NCHUNK
    int*   pidx = (int*)(pmax + NP * NCHUNK);   // NP*NCHUNK
    int*   nn   = pidx + NP * NCHUNK;   // NP
    float* lacc = (float*)(nn + NP);    // 1

    hipLaunchKernelGGL(knorm, dim3(2 * NP / 256), dim3(256), 0, stream,
                       X, Y, Xf, Xf_out, Yf, YfT, lacc);
    hipLaunchKernelGGL(ksim, dim3(NP / BN, NCHUNK), dim3(384), 0, stream,
                       Xf, Yf, pmax, pidx);
    hipLaunchKernelGGL(kred, dim3((NP + 255) / 256), dim3(256), 0, stream,
                       pmax, pidx, nn);
    hipLaunchKernelGGL(kgather, dim3(NP / 64, DC / 64), dim3(256), 0, stream,
                       YfT, nn, Xf, Ysel_out, lacc);
    hipLaunchKernelGGL(kfin, dim3(1), dim3(1), 0, stream, lacc, out);
}

// Round 3
// 742.416 us; speedup vs baseline: 1.7814x; 1.7814x over previous
//
#include <hip/hip_runtime.h>
#include <math.h>

// Problem constants (B=1 fixed by reference)
#define NP 9216          // S*S spatial positions
#define DC 256           // channels
#define DN (DC * NP)

#define FEPS 2.220446049250313e-16f

// async global->LDS, 16B per lane, no VGPR round-trip.
// LDS dest must be wave-uniform base + lane*16 — our staging maps satisfy
// this exactly (flat LDS offset == tid*16B, see ksim).
__device__ __forceinline__ void gload16(const float* g, float* l)
{
    __builtin_amdgcn_global_load_lds(
        (const __attribute__((address_space(1))) unsigned int*)g,
        (__attribute__((address_space(3))) unsigned int*)l,
        16, 0, 0);
}

// ---------------- Kernel 1: L2-normalize over channel dim ----------------
__global__ __launch_bounds__(256) void knorm(
    const float* __restrict__ X, const float* __restrict__ Y,
    float* __restrict__ Xf, float* __restrict__ Xf_out,
    float* __restrict__ Yf, float* __restrict__ YfT,
    float* __restrict__ lacc)
{
    int t = blockIdx.x * 256 + threadIdx.x;
    if (t == 0) *lacc = 0.0f;   // zero loss accumulator (ws is re-poisoned each call)

    const float* src = (t < NP) ? X : Y;
    int n = (t < NP) ? t : t - NP;

    float s = 0.0f;
    #pragma unroll 8
    for (int d = 0; d < DC; ++d) {
        float v = src[d * NP + n];
        s = fmaf(v, v, s);
    }
    float inv = 1.0f / (sqrtf(s) + FEPS);

    if (t < NP) {
        #pragma unroll 4
        for (int d = 0; d < DC; ++d) {
            float v = src[d * NP + n] * inv;
            Xf[d * NP + n] = v;
            Xf_out[d * NP + n] = v;
        }
    } else {
        #pragma unroll 4
        for (int d = 0; d < DC; ++d) {
            float v = src[d * NP + n] * inv;
            Yf[d * NP + n] = v;
            YfT[n * DC + d] = v;
        }
    }
}

// ---------------- Kernel 2: fused sim-GEMM + per-row argmax ----------------
// C[n,m] = sum_d Xf[d,n]*Yf[d,m]; running (max,idx), never materialized.
// BN=96 x BM=128 tile, BK=16, 384 threads, 4x8 acc/thread.
// Grid: 96 n-bands x 12 m-chunks = 1152 blocks = 4.5/CU.
//
// R3: staging via global_load_lds (zero staging VGPRs — R2's register
// spill cause), LDS double-buffer, ONE barrier per kt. Conflict-free
// column map {tx*4, 64+tx*4} kept from R2 (conflicts measured 0).
#define BN 96
#define BM 128
#define BK 16
#define NCHUNK 12
#define MCHUNK (NP / NCHUNK)          // 768
#define MT_PER_CHUNK (MCHUNK / BM)    // 6

__global__ __launch_bounds__(384) void ksim(
    const float* __restrict__ Xf, const float* __restrict__ Yf,
    float* __restrict__ pmax, int* __restrict__ pidx)
{
    __shared__ float As[2][BK][BN];   // 2 x 16 x 96  (6 KB each)
    __shared__ float Bs[2][BK][BM];   // 2 x 16 x 128 (8 KB each)

    const int tid = threadIdx.x;
    const int tx = tid & 15;       // 16 col-groups
    const int ty = tid >> 4;       // 24 row-groups (4 rows each)
    const int n0 = blockIdx.x * BN;
    const int mbase = blockIdx.y * MCHUNK;

    // staging maps. Flat LDS offset == tid*16B for both (row-size divides
    // thread count evenly), satisfying global_load_lds's contiguity rule.
    const int ar = tid / 24, ac = (tid % 24) * 4;     // A: 16x96 = 384 f4
    const int br = tid >> 5, bc = (tid & 31) * 4;     // B: first 384 f4
    const int e2 = tid + 384;
    const int br2 = e2 >> 5, bc2 = (e2 & 31) * 4;     // B: last 128 f4 (tid<128)

    float* const a_dst  = &As[0][0][0] + 4 * tid;     // +1536 floats for buf1
    float* const b_dst  = &Bs[0][0][0] + 4 * tid;     // +2048 floats for buf1
    float* const b_dst2 = &Bs[0][0][0] + 4 * e2;

    float best[4];
    int   bidx[4];
    #pragma unroll
    for (int i = 0; i < 4; ++i) { best[i] = -INFINITY; bidx[i] = 0; }

    for (int mt = 0; mt < MT_PER_CHUNK; ++mt) {
        const int m0 = mbase + mt * BM;

        const float* Ag  = Xf + ar * NP + n0 + ac;
        const float* Bg  = Yf + br * NP + m0 + bc;
        const float* Bg2 = Yf + br2 * NP + m0 + bc2;

        // prologue: async-stage kt=0 into buffer 0
        gload16(Ag, a_dst);
        gload16(Bg, b_dst);
        if (tid < 128) gload16(Bg2, b_dst2);
        __syncthreads();   // vmcnt drain + barrier: buf0 ready

        float acc[4][8];
        #pragma unroll
        for (int i = 0; i < 4; ++i)
            #pragma unroll
            for (int j = 0; j < 8; ++j) acc[i][j] = 0.0f;

        int cur = 0;
        for (int kt = 0; kt < DC / BK; ++kt) {
            // async prefetch kt+1 into the other buffer (no wait here;
            // the end-of-iteration barrier drains it ~1000 cycles later)
            if (kt < DC / BK - 1) {
                Ag += BK * NP; Bg += BK * NP; Bg2 += BK * NP;
                const int o = (cur ^ 1);
                gload16(Ag, a_dst + o * (BK * BN));
                gload16(Bg, b_dst + o * (BK * BM));
                if (tid < 128) gload16(Bg2, b_dst2 + o * (BK * BM));
            }

            // compute on buffer `cur`
            const float* Ab  = &As[cur][0][ty * 4];
            const float* Bb0 = &Bs[cur][0][tx * 4];
            const float* Bb1 = &Bs[cur][0][64 + tx * 4];
            #pragma unroll
            for (int k = 0; k < BK; ++k) {
                const float4 a  = *(const float4*)(Ab  + k * BN);
                const float4 b0 = *(const float4*)(Bb0 + k * BM);
                const float4 b1 = *(const float4*)(Bb1 + k * BM);
                const float av[4] = {a.x, a.y, a.z, a.w};
                const float bv[8] = {b0.x, b0.y, b0.z, b0.w,
                                     b1.x, b1.y, b1.z, b1.w};
                #pragma unroll
                for (int i = 0; i < 4; ++i)
                    #pragma unroll
                    for (int j = 0; j < 8; ++j)
                        acc[i][j] = fmaf(av[i], bv[j], acc[i][j]);
            }
            __syncthreads();   // all waves done reading cur; prefetch landed
            cur ^= 1;
        }

        // Fold this m-tile into the running argmax. Thread's columns are
        // ascending in j (j<4 -> m0+tx*4+j, j>=4 -> m0+64+tx*4+j-4);
        // strict '>' keeps the FIRST max (jnp.argmax tie semantics).
        #pragma unroll
        for (int i = 0; i < 4; ++i)
            #pragma unroll
            for (int j = 0; j < 8; ++j) {
                float v = acc[i][j];
                int col = (j < 4) ? (m0 + tx * 4 + j)
                                  : (m0 + 64 + tx * 4 + (j - 4));
                if (v > best[i]) { best[i] = v; bidx[i] = col; }
            }
    }

    // Reduce across the 16 tx lanes (same rows). xor<16 stays in group.
    #pragma unroll
    for (int off = 1; off < 16; off <<= 1) {
        #pragma unroll
        for (int i = 0; i < 4; ++i) {
            float ov = __shfl_xor(best[i], off, 64);
            int   oi = __shfl_xor(bidx[i], off, 64);
            if (ov > best[i] || (ov == best[i] && oi < bidx[i])) {
                best[i] = ov; bidx[i] = oi;
            }
        }
    }

    if (tx == 0) {
        #pragma unroll
        for (int i = 0; i < 4; ++i) {
            int row = n0 + ty * 4 + i;
            pmax[row * NCHUNK + blockIdx.y] = best[i];
            pidx[row * NCHUNK + blockIdx.y] = bidx[i];
        }
    }
}

// ---------------- Kernel 3: reduce chunk partials -> nn_idx ----------------
__global__ __launch_bounds__(256) void kred(
    const float* __restrict__ pmax, const int* __restrict__ pidx,
    int* __restrict__ nn)
{
    int t = blockIdx.x * 256 + threadIdx.x;
    if (t >= NP) return;
    float b = -INFINITY;
    int bi = 0x7fffffff;
    #pragma unroll
    for (int c = 0; c < NCHUNK; ++c) {
        float v = pmax[t * NCHUNK + c];
        int  id = pidx[t * NCHUNK + c];
        if (v > b || (v == b && id < bi)) { b = v; bi = id; }
    }
    nn[t] = bi;
}

// ---------------- Kernel 4: gather Y_sel + fused MSE loss ----------------
__global__ __launch_bounds__(256) void kgather(
    const float* __restrict__ YfT, const int* __restrict__ nn,
    const float* __restrict__ Xf, float* __restrict__ Ysel,
    float* __restrict__ lacc)
{
    __shared__ float tile[64][65];
    __shared__ int   idxs[64];
    __shared__ float wsum[4];

    const int n0 = blockIdx.x * 64;
    const int d0 = blockIdx.y * 64;
    const int tid = threadIdx.x;

    if (tid < 64) idxs[tid] = nn[n0 + tid];
    __syncthreads();

    const int c  = tid & 63;   // lane within wave
    const int r0 = tid >> 6;   // wave id 0..3

    #pragma unroll
    for (int s = 0; s < 16; ++s) {
        int r = s * 4 + r0;    // n-row within tile; whole wave shares r
        tile[r][c] = YfT[(long)idxs[r] * DC + d0 + c];
    }
    __syncthreads();

    float lsum = 0.0f;
    #pragma unroll
    for (int s = 0; s < 16; ++s) {
        int a = s * 4 + r0;            // d-offset within tile
        int d = d0 + a;
        int n = n0 + c;
        float y = tile[c][a];          // stride-65 read: conflict-free
        float x = Xf[(long)d * NP + n];
        float diff = x - y;
        lsum = fmaf(diff, diff, lsum);
        Ysel[(long)d * NP + n] = y;    // coalesced over n
    }

    #pragma unroll
    for (int off = 32; off >= 1; off >>= 1)
        lsum += __shfl_xor(lsum, off, 64);
    if ((tid & 63) == 0) wsum[tid >> 6] = lsum;
    __syncthreads();
    if (tid == 0)
        atomicAdd(lacc, wsum[0] + wsum[1] + wsum[2] + wsum[3]);
}

// ---------------- Kernel 5: finalize loss ----------------
__global__ void kfin(const float* __restrict__ lacc, float* __restrict__ out)
{
    out[0] = lacc[0] * (1.0f / (float)DN);
}

extern "C" void kernel_launch(void* const* d_in, const int* in_sizes, int n_in,
                              void* d_out, int out_size, void* d_ws, size_t ws_size,
                              hipStream_t stream)
{
    const float* X = (const float*)d_in[0];   // X_features [1,256,96,96]
    const float* Y = (const float*)d_in[1];   // Y_features [1,256,96,96]
    // d_in[2], d_in[3] (images) are dead code in the reference — unused.

    float* out = (float*)d_out;
    float* Ysel_out = out + 1;          // output 1: Y_sel [1,D,N]
    float* Xf_out   = out + 1 + DN;     // output 2: Xf   [1,D,N]

    float* Xf   = (float*)d_ws;         // DN
    float* Yf   = Xf + DN;              // DN
    float* YfT  = Yf + DN;              // DN  ([N,D] transposed)
    float* pmax = YfT + DN;             // NP*NCHUNK
    int*   pidx = (int*)(pmax + NP * NCHUNK);   // NP*NCHUNK
    int*   nn   = pidx + NP * NCHUNK;   // NP
    float* lacc = (float*)(nn + NP);    // 1

    hipLaunchKernelGGL(knorm, dim3(2 * NP / 256), dim3(256), 0, stream,
                       X, Y, Xf, Xf_out, Yf, YfT, lacc);
    hipLaunchKernelGGL(ksim, dim3(NP / BN, NCHUNK), dim3(384), 0, stream,
                       Xf, Yf, pmax, pidx);
    hipLaunchKernelGGL(kred, dim3((NP + 255) / 256), dim3(256), 0, stream,
                       pmax, pidx, nn);
    hipLaunchKernelGGL(kgather, dim3(NP / 64, DC / 64), dim3(256), 0, stream,
                       YfT, nn, Xf, Ysel_out, lacc);
    hipLaunchKernelGGL(kfin, dim3(1), dim3(1), 0, stream, lacc, out);
}

// Round 5
// 381.218 us; speedup vs baseline: 3.4692x; 1.9475x over previous
//
#include <hip/hip_runtime.h>
#include <math.h>

// Problem constants (B=1 fixed by reference)
#define NP 9216          // S*S spatial positions
#define DC 256           // channels
#define DN (DC * NP)
#define NT 72            // 9216 / 128 tiles per dim

#define FEPS 2.220446049250313e-16f

typedef __attribute__((ext_vector_type(8))) _Float16 half8v;
typedef __attribute__((ext_vector_type(4))) float   float4v;

// async global->LDS, 16B/lane, no VGPR round-trip. LDS dest must be
// wave-uniform base + lane*16 (m104/m108) — all our staging maps are
// flat tid*16.
__device__ __forceinline__ void gload16(const void* g, void* l)
{
    __builtin_amdgcn_global_load_lds(
        (const __attribute__((address_space(1))) unsigned int*)g,
        (__attribute__((address_space(3))) unsigned int*)l,
        16, 0, 0);
}

union HU { _Float16 h; unsigned short u; };
__device__ __forceinline__ unsigned short f2h(float f) { HU x; x.h = (_Float16)f; return x.u; }
__device__ __forceinline__ float h2f(unsigned short s) { HU x; x.u = s; return (float)x.h; }

// ---------------- Kernel 1: normalize + fp16 split-encode ----------------
// v = f/||f||. Split: H = fp16(v*2^8); L = fp16((v*2^8 - H)*2^11)  (exact
// residual; scaling avoids fp16 denormal flush). Planes stored [n][d] so
// MFMA fragments read 8 consecutive k. X also writes exact fp32 Xf to out.
__global__ __launch_bounds__(256) void knorm(
    const float* __restrict__ X, const float* __restrict__ Y,
    float* __restrict__ Xf_out,
    unsigned short* __restrict__ XH, unsigned short* __restrict__ XL,
    unsigned short* __restrict__ YH, unsigned short* __restrict__ YL,
    float* __restrict__ lacc)
{
    int t = blockIdx.x * 256 + threadIdx.x;
    if (t == 0) *lacc = 0.0f;   // ws is re-poisoned each call

    bool isX = t < NP;
    const float* src = isX ? X : Y;
    int n = isX ? t : t - NP;

    float s = 0.0f;
    #pragma unroll 8
    for (int d = 0; d < DC; ++d) {
        float v = src[d * NP + n];
        s = fmaf(v, v, s);
    }
    float inv = 1.0f / (sqrtf(s) + FEPS);

    unsigned* hT = (unsigned*)(isX ? XH : YH);
    unsigned* lT = (unsigned*)(isX ? XL : YL);
    const int rowb = (n * DC) >> 1;   // uint index of row start

    #pragma unroll 4
    for (int d = 0; d < DC; d += 2) {
        float v0 = src[d * NP + n] * inv;
        float v1 = src[(d + 1) * NP + n] * inv;
        float s0 = v0 * 256.0f, s1 = v1 * 256.0f;
        unsigned short h0 = f2h(s0), h1 = f2h(s1);
        unsigned short l0 = f2h((s0 - h2f(h0)) * 2048.0f);
        unsigned short l1 = f2h((s1 - h2f(h1)) * 2048.0f);
        hT[rowb + (d >> 1)] = (unsigned)h0 | ((unsigned)h1 << 16);
        lT[rowb + (d >> 1)] = (unsigned)l0 | ((unsigned)l1 << 16);
        if (isX) {
            Xf_out[d * NP + n]       = v0;
            Xf_out[(d + 1) * NP + n] = v1;
        }
    }
}

// ---------------- Kernel 2: MFMA sim-GEMM + fused per-row argmax ----------
// 128x128 output tile per block, BK=32, 256 threads = 4 waves (2x2 of
// 64x64), 16x16x32 f16 MFMA. acc holds sim*2^16 = Hx·Hy + 2^-11(Hx·Ly+Lx·Hy).
// LDS: 4 planes (Ah|Al|Bh|Bl) x 128x32 fp16 = 32 KB single-buffered, filled
// by global_load_lds w16. Chunk-XOR swizzle c = m*4 + (q ^ ((m>>1)&3)) makes
// fragment ds_read_b128s 2-way-per-bank (free, m136) while staging stays
// lane-linear (hardware-required).
//
// R5 fix: waves 0/1 (and 2/3) cover the SAME rows with different column
// halves — R4 had both racing on one pmax slot per (tile,row). Now each
// wave writes its own (tile, col-half) partial: slot (2*tileY+half)*NP+row.
__global__ __launch_bounds__(256, 3) void ksim(
    const unsigned short* __restrict__ XH, const unsigned short* __restrict__ XL,
    const unsigned short* __restrict__ YH, const unsigned short* __restrict__ YL,
    float* __restrict__ pmax, int* __restrict__ pidx)
{
    __shared__ unsigned short LB[4 * 128 * 32];   // 32 KB

    const int t  = threadIdx.x;
    const int n0 = blockIdx.x * 128;
    const int m0 = blockIdx.y * 128;

    // ---- staging maps: 8 chunks/thread, flat slot s = i*256+t ----
    // plane p=i>>1 (Ah,Al,Bh,Bl), in-plane chunk c=(i&1)*256+t,
    // row m=c>>2, q=(c&3)^((m>>1)&3)  [q invariant under m+=64]
    const int mA = t >> 2;
    const int qA = (t & 3) ^ ((mA >> 1) & 3);
    const size_t oLo = (size_t)mA * DC + qA * 8;
    const size_t oHi = (size_t)(mA + 64) * DC + qA * 8;

    const unsigned short* g0 = XH + (size_t)n0 * DC + oLo;
    const unsigned short* g1 = XH + (size_t)n0 * DC + oHi;
    const unsigned short* g2 = XL + (size_t)n0 * DC + oLo;
    const unsigned short* g3 = XL + (size_t)n0 * DC + oHi;
    const unsigned short* g4 = YH + (size_t)m0 * DC + oLo;
    const unsigned short* g5 = YH + (size_t)m0 * DC + oHi;
    const unsigned short* g6 = YL + (size_t)m0 * DC + oLo;
    const unsigned short* g7 = YL + (size_t)m0 * DC + oHi;

    char* lb = (char*)LB;
    char* const d0 = lb + 0 * 4096 + t * 16;
    char* const d1 = lb + 1 * 4096 + t * 16;
    char* const d2 = lb + 2 * 4096 + t * 16;
    char* const d3 = lb + 3 * 4096 + t * 16;
    char* const d4 = lb + 4 * 4096 + t * 16;
    char* const d5 = lb + 5 * 4096 + t * 16;
    char* const d6 = lb + 6 * 4096 + t * 16;
    char* const d7 = lb + 7 * 4096 + t * 16;

    // ---- compute-lane maps (A: rows n, B: cols m) ----
    const int L   = t & 63;
    const int wid = t >> 6;
    const int wnb = (wid >> 1) * 64;   // wave n-offset in tile
    const int wmb = (wid & 1) * 64;    // wave m-offset in tile
    const int lc  = L & 15;
    const int lq  = L >> 4;

    const int mAr = wnb + lc;
    const int cA0 = mAr * 4 + (lq ^ ((mAr >> 1) & 3));
    const int mBr = wmb + lc;
    const int cB0 = mBr * 4 + (lq ^ ((mBr >> 1) & 3));

    const char* aAh = lb + cA0 * 16;            // plane Ah at 0
    const char* aAl = aAh + 8192;               // Al
    const char* aBh = lb + 16384 + cB0 * 16;    // Bh
    const char* aBl = aBh + 8192;               // Bl

    float4v acc[4][4];
    #pragma unroll
    for (int i = 0; i < 4; ++i)
        #pragma unroll
        for (int j = 0; j < 4; ++j)
            acc[i][j] = (float4v){0.f, 0.f, 0.f, 0.f};
    const float4v z4 = (float4v){0.f, 0.f, 0.f, 0.f};
    const float CS = 1.0f / 2048.0f;   // 2^-11 cross-term scale

    // prologue: stage kt=0
    gload16(g0, d0); gload16(g1, d1); gload16(g2, d2); gload16(g3, d3);
    gload16(g4, d4); gload16(g5, d5); gload16(g6, d6); gload16(g7, d7);
    g0 += 32; g1 += 32; g2 += 32; g3 += 32;
    g4 += 32; g5 += 32; g6 += 32; g7 += 32;

    for (int kt = 0; kt < DC / 32; ++kt) {
        __syncthreads();   // vmcnt drain: tile kt resident

        half8v Ah[4], Al[4];
        #pragma unroll
        for (int rb = 0; rb < 4; ++rb) {
            Ah[rb] = *(const half8v*)(aAh + rb * 1024);
            Al[rb] = *(const half8v*)(aAl + rb * 1024);
        }
        #pragma unroll
        for (int cb = 0; cb < 4; ++cb) {
            const half8v Bh = *(const half8v*)(aBh + cb * 1024);
            const half8v Bl = *(const half8v*)(aBl + cb * 1024);
            #pragma unroll
            for (int rb = 0; rb < 4; ++rb) {
                float4v tv;
                tv = __builtin_amdgcn_mfma_f32_16x16x32_f16(Al[rb], Bh, z4, 0, 0, 0);
                tv = __builtin_amdgcn_mfma_f32_16x16x32_f16(Ah[rb], Bl, tv, 0, 0, 0);
                acc[rb][cb] = __builtin_amdgcn_mfma_f32_16x16x32_f16(Ah[rb], Bh, acc[rb][cb], 0, 0, 0);
                acc[rb][cb].x = fmaf(tv.x, CS, acc[rb][cb].x);
                acc[rb][cb].y = fmaf(tv.y, CS, acc[rb][cb].y);
                acc[rb][cb].z = fmaf(tv.z, CS, acc[rb][cb].z);
                acc[rb][cb].w = fmaf(tv.w, CS, acc[rb][cb].w);
            }
        }

        __syncthreads();   // everyone done reading tile kt
        if (kt < DC / 32 - 1) {
            gload16(g0, d0); gload16(g1, d1); gload16(g2, d2); gload16(g3, d3);
            gload16(g4, d4); gload16(g5, d5); gload16(g6, d6); gload16(g7, d7);
            g0 += 32; g1 += 32; g2 += 32; g3 += 32;
            g4 += 32; g5 += 32; g6 += 32; g7 += 32;
        }
    }

    // ---- epilogue: per-row argmax. C/D map: col=lane&15, row=lq*4+reg ----
    // Values stay in sim*2^16 units (monotonic scale — argmax invariant).
    float bv[16]; int bc[16];
    #pragma unroll
    for (int s = 0; s < 16; ++s) { bv[s] = -INFINITY; bc[s] = 0; }

    #pragma unroll
    for (int rb = 0; rb < 4; ++rb)
        #pragma unroll
        for (int cb = 0; cb < 4; ++cb) {   // cb ascending = col ascending (first-max kept)
            const int col = m0 + wmb + cb * 16 + lc;
            #pragma unroll
            for (int r = 0; r < 4; ++r) {
                float v = acc[rb][cb][r];
                int s = rb * 4 + r;
                if (v > bv[s]) { bv[s] = v; bc[s] = col; }
            }
        }

    // reduce across the 16 lc lanes (xor<16 stays in the quad-group)
    #pragma unroll
    for (int off = 1; off < 16; off <<= 1) {
        #pragma unroll
        for (int s = 0; s < 16; ++s) {
            float ov = __shfl_xor(bv[s], off, 64);
            int   oi = __shfl_xor(bc[s], off, 64);
            if (ov > bv[s] || (ov == bv[s] && oi < bc[s])) { bv[s] = ov; bc[s] = oi; }
        }
    }

    // One slot per (tile, column-half): no inter-wave race (R4's bug).
    if (lc == 0) {
        const int slot = blockIdx.y * 2 + (wmb >> 6);   // ascending col order
        #pragma unroll
        for (int rb = 0; rb < 4; ++rb)
            #pragma unroll
            for (int r = 0; r < 4; ++r) {
                int row = n0 + wnb + rb * 16 + lq * 4 + r;
                pmax[(size_t)slot * NP + row] = bv[rb * 4 + r];
                pidx[(size_t)slot * NP + row] = bc[rb * 4 + r];
            }
    }
}

// ---------------- Kernel 3: reduce 144 half-tile partials -> nn_idx -------
// Slots ascending == column ranges ascending, so '>' + lower-id-on-tie
// preserves jnp.argmax first-max semantics.
__global__ __launch_bounds__(256) void kred(
    const float* __restrict__ pmax, const int* __restrict__ pidx,
    int* __restrict__ nn)
{
    int t = blockIdx.x * 256 + threadIdx.x;
    if (t >= NP) return;
    float b = -INFINITY;
    int bi = 0x7fffffff;
    for (int c = 0; c < 2 * NT; ++c) {
        float v = pmax[(size_t)c * NP + t];
        int  id = pidx[(size_t)c * NP + t];
        if (v > b || (v == b && id < bi)) { b = v; bi = id; }
    }
    nn[t] = bi;
}

// ---------------- Kernel 4: gather Y_sel + fused MSE loss ----------------
// Y value reconstructed from split planes: y = H*2^-8 + L*2^-19
// (<=6e-8 from exact fp32 — far inside the 6.2e-3 threshold).
__global__ __launch_bounds__(256) void kgather(
    const unsigned short* __restrict__ YH, const unsigned short* __restrict__ YL,
    const int* __restrict__ nn,
    const float* __restrict__ Xf, float* __restrict__ Ysel,
    float* __restrict__ lacc)
{
    __shared__ float tile[64][65];
    __shared__ int   idxs[64];
    __shared__ float wsum[4];

    const int n0 = blockIdx.x * 64;
    const int d0 = blockIdx.y * 64;
    const int tid = threadIdx.x;

    if (tid < 64) idxs[tid] = nn[n0 + tid];
    __syncthreads();

    const int c  = tid & 63;
    const int r0 = tid >> 6;

    #pragma unroll
    for (int s = 0; s < 16; ++s) {
        int r = s * 4 + r0;
        long base = (long)idxs[r] * DC + d0 + c;
        tile[r][c] = h2f(YH[base]) * (1.0f / 256.0f)
                   + h2f(YL[base]) * (1.0f / 524288.0f);   // 2^-19
    }
    __syncthreads();

    float lsum = 0.0f;
    #pragma unroll
    for (int s = 0; s < 16; ++s) {
        int a = s * 4 + r0;
        int d = d0 + a;
        int n = n0 + c;
        float y = tile[c][a];          // stride-65: conflict-free
        float x = Xf[(long)d * NP + n];
        float diff = x - y;
        lsum = fmaf(diff, diff, lsum);
        Ysel[(long)d * NP + n] = y;    // coalesced over n
    }

    #pragma unroll
    for (int off = 32; off >= 1; off >>= 1)
        lsum += __shfl_xor(lsum, off, 64);
    if ((tid & 63) == 0) wsum[tid >> 6] = lsum;
    __syncthreads();
    if (tid == 0)
        atomicAdd(lacc, wsum[0] + wsum[1] + wsum[2] + wsum[3]);
}

// ---------------- Kernel 5: finalize loss ----------------
__global__ void kfin(const float* __restrict__ lacc, float* __restrict__ out)
{
    out[0] = lacc[0] * (1.0f / (float)DN);
}

extern "C" void kernel_launch(void* const* d_in, const int* in_sizes, int n_in,
                              void* d_out, int out_size, void* d_ws, size_t ws_size,
                              hipStream_t stream)
{
    const float* X = (const float*)d_in[0];   // X_features [1,256,96,96]
    const float* Y = (const float*)d_in[1];   // Y_features [1,256,96,96]
    // d_in[2], d_in[3] (images) are dead code in the reference — unused.

    float* out = (float*)d_out;
    float* Ysel_out = out + 1;          // output 1: Y_sel [1,D,N]
    float* Xf_out   = out + 1 + DN;     // output 2: Xf   [1,D,N]  (exact fp32)

    // Workspace (~29.5 MB)
    unsigned short* XH = (unsigned short*)d_ws;   // DN halves each
    unsigned short* XL = XH + DN;
    unsigned short* YH = XL + DN;
    unsigned short* YL = YH + DN;
    float* pmax = (float*)(YL + DN);                    // 2*NT*NP
    int*   pidx = (int*)(pmax + (size_t)2 * NT * NP);   // 2*NT*NP
    int*   nn   = pidx + (size_t)2 * NT * NP;           // NP
    float* lacc = (float*)(nn + NP);                    // 1

    hipLaunchKernelGGL(knorm, dim3(2 * NP / 256), dim3(256), 0, stream,
                       X, Y, Xf_out, XH, XL, YH, YL, lacc);
    hipLaunchKernelGGL(ksim, dim3(NT, NT), dim3(256), 0, stream,
                       XH, XL, YH, YL, pmax, pidx);
    hipLaunchKernelGGL(kred, dim3(NP / 256), dim3(256), 0, stream,
                       pmax, pidx, nn);
    hipLaunchKernelGGL(kgather, dim3(NP / 64, DC / 64), dim3(256), 0, stream,
                       YH, YL, nn, Xf_out, Ysel_out, lacc);
    hipLaunchKernelGGL(kfin, dim3(1), dim3(1), 0, stream, lacc, out);
}

// Round 6
// 337.372 us; speedup vs baseline: 3.9201x; 1.1300x over previous
//
#include <hip/hip_runtime.h>
#include <math.h>

// Problem constants (B=1 fixed by reference)
#define NP 9216          // S*S spatial positions
#define DC 256           // channels
#define DN (DC * NP)
#define NT 72            // 9216 / 128 tiles per dim

#define FEPS 2.220446049250313e-16f

typedef __attribute__((ext_vector_type(8))) _Float16 half8v;
typedef __attribute__((ext_vector_type(4))) float   float4v;

// async global->LDS, 16B/lane, no VGPR round-trip. LDS dest must be
// wave-uniform base + lane*16 (m104/m108) — all staging maps are flat tid*16.
__device__ __forceinline__ void gload16(const void* g, void* l)
{
    __builtin_amdgcn_global_load_lds(
        (const __attribute__((address_space(1))) unsigned int*)g,
        (__attribute__((address_space(3))) unsigned int*)l,
        16, 0, 0);
}

union HU { _Float16 h; unsigned short u; };
__device__ __forceinline__ unsigned short f2h(float f) { HU x; x.h = (_Float16)f; return x.u; }
__device__ __forceinline__ float h2f(unsigned short s) { HU x; x.u = s; return (float)x.h; }

// ---------------- Kernel 1a: inverse L2 norms ----------------
__global__ __launch_bounds__(256) void knormA(
    const float* __restrict__ X, const float* __restrict__ Y,
    float* __restrict__ inv, float* __restrict__ lacc)
{
    int t = blockIdx.x * 256 + threadIdx.x;
    if (t == 0) *lacc = 0.0f;   // ws is re-poisoned each call

    bool isX = t < NP;
    const float* src = isX ? X : Y;
    int n = isX ? t : t - NP;

    float s = 0.0f;
    #pragma unroll 8
    for (int d = 0; d < DC; ++d) {
        float v = src[d * NP + n];
        s = fmaf(v, v, s);
    }
    inv[t] = 1.0f / (sqrtf(s) + FEPS);
}

// ---------------- Kernel 1b: scale + fp16 split + transposed write -------
// Split: H = fp16(v*2^8); L = fp16((v*2^8 - H)*2^11) (exact residual).
// Planes stored [n][d]. R6: LDS-transpose per 64n x 64d chunk so the
// [n][d] plane writes are coalesced uints (R5's knorm scattered 4B stores
// ~16x write-amplified). Xf_out ([d][n]) stays coalesced as-is.
__global__ __launch_bounds__(256) void knormB(
    const float* __restrict__ X, const float* __restrict__ Y,
    const float* __restrict__ inv,
    float* __restrict__ Xf_out,
    unsigned short* __restrict__ XH, unsigned short* __restrict__ XL,
    unsigned short* __restrict__ YH, unsigned short* __restrict__ YL)
{
    __shared__ unsigned short Hs[64][66];   // [n][d], +2 pad: conflict-free
    __shared__ unsigned short Ls[64][66];
    __shared__ float invs[64];

    const int t = threadIdx.x;
    const bool isX = (blockIdx.y == 0);
    const float* src = isX ? X : Y;
    unsigned* hT = (unsigned*)(isX ? XH : YH);
    unsigned* lT = (unsigned*)(isX ? XL : YL);
    const int n0 = blockIdx.x * 64;

    if (t < 64) invs[t] = inv[(isX ? 0 : NP) + n0 + t];
    __syncthreads();

    const int nl  = t & 63;    // load-phase lane -> n (coalesced)
    const int dl0 = t >> 6;    // 0..3
    const int nr  = t >> 5;    // write-phase row group 0..7
    const int du  = t & 31;    // write-phase uint-in-chunk

    for (int ch = 0; ch < 4; ++ch) {
        const int d0 = ch * 64;
        #pragma unroll
        for (int s = 0; s < 16; ++s) {
            int dl = s * 4 + dl0;
            int d  = d0 + dl;
            float v = src[(size_t)d * NP + n0 + nl] * invs[nl];
            if (isX) Xf_out[(size_t)d * NP + n0 + nl] = v;
            float sv = v * 256.0f;
            unsigned short h = f2h(sv);
            unsigned short l = f2h((sv - h2f(h)) * 2048.0f);
            Hs[nl][dl] = h;
            Ls[nl][dl] = l;
        }
        __syncthreads();
        #pragma unroll
        for (int p = 0; p < 8; ++p) {
            int rl = p * 8 + nr;                       // row-local 0..63
            unsigned h = *(const unsigned*)&Hs[rl][2 * du];
            unsigned l = *(const unsigned*)&Ls[rl][2 * du];
            int n = n0 + rl;
            hT[n * 128 + ch * 32 + du] = h;            // coalesced
            lT[n * 128 + ch * 32 + du] = l;
        }
        __syncthreads();
    }
}

// ---------------- Kernel 2: MFMA sim-GEMM + fused per-row argmax ----------
// 128x128 tile/block, BK=32, 4 waves (2x2 of 64x64), 16x16x32 f16 MFMA.
// sim*2^16 = Hx·Hy + 2^-11(Hx·Ly + Lx·Hy) — dual accumulators, folded once.
// R6: LDS double-buffer (2x32 KB), ONE barrier/kt; prefetch issued right
// after the barrier -> drained at the NEXT barrier with a full compute
// phase in its shadow (R5's single-buffer exposed full global latency/kt).
// Chunk-XOR swizzle keeps fragment ds_read_b128s conflict-free while
// staging stays lane-linear.
__global__ __launch_bounds__(256, 2) void ksim(
    const unsigned short* __restrict__ XH, const unsigned short* __restrict__ XL,
    const unsigned short* __restrict__ YH, const unsigned short* __restrict__ YL,
    float* __restrict__ pmax, int* __restrict__ pidx)
{
    __shared__ unsigned short LB[2 * 16384];   // 2 buffers x 32 KB

    const int t  = threadIdx.x;
    const int n0 = blockIdx.x * 128;
    const int m0 = blockIdx.y * 128;

    // staging maps: 8 half-plane chunks/thread, flat LDS slot = tid*16B
    const int mA = t >> 2;
    const int qA = (t & 3) ^ ((mA >> 1) & 3);
    const size_t oLo = (size_t)mA * DC + qA * 8;
    const size_t oHi = (size_t)(mA + 64) * DC + qA * 8;

    const unsigned short* g0 = XH + (size_t)n0 * DC + oLo;
    const unsigned short* g1 = XH + (size_t)n0 * DC + oHi;
    const unsigned short* g2 = XL + (size_t)n0 * DC + oLo;
    const unsigned short* g3 = XL + (size_t)n0 * DC + oHi;
    const unsigned short* g4 = YH + (size_t)m0 * DC + oLo;
    const unsigned short* g5 = YH + (size_t)m0 * DC + oHi;
    const unsigned short* g6 = YL + (size_t)m0 * DC + oLo;
    const unsigned short* g7 = YL + (size_t)m0 * DC + oHi;

    char* lb = (char*)LB;
    char* const d0 = lb + 0 * 4096 + t * 16;
    char* const d1 = lb + 1 * 4096 + t * 16;
    char* const d2 = lb + 2 * 4096 + t * 16;
    char* const d3 = lb + 3 * 4096 + t * 16;
    char* const d4 = lb + 4 * 4096 + t * 16;
    char* const d5 = lb + 5 * 4096 + t * 16;
    char* const d6 = lb + 6 * 4096 + t * 16;
    char* const d7 = lb + 7 * 4096 + t * 16;

    // compute-lane maps
    const int L   = t & 63;
    const int wid = t >> 6;
    const int wnb = (wid >> 1) * 64;   // wave n-offset
    const int wmb = (wid & 1) * 64;    // wave m-offset
    const int lc  = L & 15;
    const int lq  = L >> 4;

    const int mAr = wnb + lc;
    const int cA0 = mAr * 4 + (lq ^ ((mAr >> 1) & 3));
    const int mBr = wmb + lc;
    const int cB0 = mBr * 4 + (lq ^ ((mBr >> 1) & 3));

    const char* aAh = lb + cA0 * 16;            // Ah plane at 0
    const char* aAl = aAh + 8192;               // Al
    const char* aBh = lb + 16384 + cB0 * 16;    // Bh
    const char* aBl = aBh + 8192;               // Bl

    float4v accH[4][4], accC[4][4];
    #pragma unroll
    for (int i = 0; i < 4; ++i)
        #pragma unroll
        for (int j = 0; j < 4; ++j) {
            accH[i][j] = (float4v){0.f, 0.f, 0.f, 0.f};
            accC[i][j] = (float4v){0.f, 0.f, 0.f, 0.f};
        }

    // prologue: stage kt=0 into buffer 0
    gload16(g0, d0); gload16(g1, d1); gload16(g2, d2); gload16(g3, d3);
    gload16(g4, d4); gload16(g5, d5); gload16(g6, d6); gload16(g7, d7);
    g0 += 32; g1 += 32; g2 += 32; g3 += 32;
    g4 += 32; g5 += 32; g6 += 32; g7 += 32;

    int buf = 0;
    for (int kt = 0; kt < DC / 32; ++kt) {
        // drains vmcnt (loads into `buf` complete) + all waves done with
        // the other buffer -> safe to overwrite it below.
        __syncthreads();

        if (kt < DC / 32 - 1) {
            const int bo = (buf ^ 1) * 32768;
            gload16(g0, d0 + bo); gload16(g1, d1 + bo);
            gload16(g2, d2 + bo); gload16(g3, d3 + bo);
            gload16(g4, d4 + bo); gload16(g5, d5 + bo);
            gload16(g6, d6 + bo); gload16(g7, d7 + bo);
            g0 += 32; g1 += 32; g2 += 32; g3 += 32;
            g4 += 32; g5 += 32; g6 += 32; g7 += 32;
        }

        const int bo = buf * 32768;
        half8v Ah[4], Al[4];
        #pragma unroll
        for (int rb = 0; rb < 4; ++rb) {
            Ah[rb] = *(const half8v*)(aAh + bo + rb * 1024);
            Al[rb] = *(const half8v*)(aAl + bo + rb * 1024);
        }
        #pragma unroll
        for (int cb = 0; cb < 4; ++cb) {
            const half8v Bh = *(const half8v*)(aBh + bo + cb * 1024);
            const half8v Bl = *(const half8v*)(aBl + bo + cb * 1024);
            #pragma unroll
            for (int rb = 0; rb < 4; ++rb) {
                accC[rb][cb] = __builtin_amdgcn_mfma_f32_16x16x32_f16(Al[rb], Bh, accC[rb][cb], 0, 0, 0);
                accC[rb][cb] = __builtin_amdgcn_mfma_f32_16x16x32_f16(Ah[rb], Bl, accC[rb][cb], 0, 0, 0);
                accH[rb][cb] = __builtin_amdgcn_mfma_f32_16x16x32_f16(Ah[rb], Bh, accH[rb][cb], 0, 0, 0);
            }
        }
        buf ^= 1;
    }

    // ---- epilogue: fold cross term once; per-row argmax ----
    // C/D map: col=lane&15, row=lq*4+reg. Scale 2^16 is argmax-invariant.
    const float CS = 1.0f / 2048.0f;
    float bv[16]; int bc[16];
    #pragma unroll
    for (int s = 0; s < 16; ++s) { bv[s] = -INFINITY; bc[s] = 0; }

    #pragma unroll
    for (int rb = 0; rb < 4; ++rb)
        #pragma unroll
        for (int cb = 0; cb < 4; ++cb) {   // cb ascending = col ascending
            const int col = m0 + wmb + cb * 16 + lc;
            #pragma unroll
            for (int r = 0; r < 4; ++r) {
                float v = fmaf(accC[rb][cb][r], CS, accH[rb][cb][r]);
                int s = rb * 4 + r;
                if (v > bv[s]) { bv[s] = v; bc[s] = col; }
            }
        }

    // reduce across the 16 lc lanes (xor<16 stays in the quad-group)
    #pragma unroll
    for (int off = 1; off < 16; off <<= 1) {
        #pragma unroll
        for (int s = 0; s < 16; ++s) {
            float ov = __shfl_xor(bv[s], off, 64);
            int   oi = __shfl_xor(bc[s], off, 64);
            if (ov > bv[s] || (ov == bv[s] && oi < bc[s])) { bv[s] = ov; bc[s] = oi; }
        }
    }

    // LDS-bounce per wave (private 1 KB region of buffer 0 — all waves are
    // past kt=7's barrier, last buf0 read was kt=6) -> coalesced writes of
    // 64 consecutive rows by 64 lanes. One slot per (tile, col-half): no
    // inter-wave race, slots ascending == column ranges ascending.
    {
        float* fs = (float*)(lb + wid * 1024);
        int*   is = (int*)(fs + 64);
        if (lc == 0) {
            #pragma unroll
            for (int rb = 0; rb < 4; ++rb)
                #pragma unroll
                for (int r = 0; r < 4; ++r) {
                    int rl = rb * 16 + lq * 4 + r;
                    fs[rl] = bv[rb * 4 + r];
                    is[rl] = bc[rb * 4 + r];
                }
        }
        // wave-internal ds write->read; compiler inserts lgkmcnt wait
        const int slot = blockIdx.y * 2 + (wmb >> 6);
        pmax[(size_t)slot * NP + n0 + wnb + L] = fs[L];
        pidx[(size_t)slot * NP + n0 + wnb + L] = is[L];
    }
}

// ---------------- Kernel 3: reduce 144 half-tile partials -> nn_idx -------
__global__ __launch_bounds__(256) void kred(
    const float* __restrict__ pmax, const int* __restrict__ pidx,
    int* __restrict__ nn)
{
    int t = blockIdx.x * 256 + threadIdx.x;
    if (t >= NP) return;
    float b = -INFINITY;
    int bi = 0x7fffffff;
    for (int c = 0; c < 2 * NT; ++c) {
        float v = pmax[(size_t)c * NP + t];
        int  id = pidx[(size_t)c * NP + t];
        if (v > b || (v == b && id < bi)) { b = v; bi = id; }
    }
    nn[t] = bi;
}

// ---------------- Kernel 4: gather Y_sel + fused MSE loss ----------------
// y = H*2^-8 + L*2^-19 (<=6e-8 from exact fp32).
__global__ __launch_bounds__(256) void kgather(
    const unsigned short* __restrict__ YH, const unsigned short* __restrict__ YL,
    const int* __restrict__ nn,
    const float* __restrict__ Xf, float* __restrict__ Ysel,
    float* __restrict__ lacc)
{
    __shared__ float tile[64][65];
    __shared__ int   idxs[64];
    __shared__ float wsum[4];

    const int n0 = blockIdx.x * 64;
    const int d0 = blockIdx.y * 64;
    const int tid = threadIdx.x;

    if (tid < 64) idxs[tid] = nn[n0 + tid];
    __syncthreads();

    const int c  = tid & 63;
    const int r0 = tid >> 6;

    #pragma unroll
    for (int s = 0; s < 16; ++s) {
        int r = s * 4 + r0;
        long base = (long)idxs[r] * DC + d0 + c;
        tile[r][c] = h2f(YH[base]) * (1.0f / 256.0f)
                   + h2f(YL[base]) * (1.0f / 524288.0f);   // 2^-19
    }
    __syncthreads();

    float lsum = 0.0f;
    #pragma unroll
    for (int s = 0; s < 16; ++s) {
        int a = s * 4 + r0;
        int d = d0 + a;
        int n = n0 + c;
        float y = tile[c][a];          // stride-65: conflict-free
        float x = Xf[(long)d * NP + n];
        float diff = x - y;
        lsum = fmaf(diff, diff, lsum);
        Ysel[(long)d * NP + n] = y;    // coalesced over n
    }

    #pragma unroll
    for (int off = 32; off >= 1; off >>= 1)
        lsum += __shfl_xor(lsum, off, 64);
    if ((tid & 63) == 0) wsum[tid >> 6] = lsum;
    __syncthreads();
    if (tid == 0)
        atomicAdd(lacc, wsum[0] + wsum[1] + wsum[2] + wsum[3]);
}

// ---------------- Kernel 5: finalize loss ----------------
__global__ void kfin(const float* __restrict__ lacc, float* __restrict__ out)
{
    out[0] = lacc[0] * (1.0f / (float)DN);
}

extern "C" void kernel_launch(void* const* d_in, const int* in_sizes, int n_in,
                              void* d_out, int out_size, void* d_ws, size_t ws_size,
                              hipStream_t stream)
{
    const float* X = (const float*)d_in[0];   // X_features [1,256,96,96]
    const float* Y = (const float*)d_in[1];   // Y_features [1,256,96,96]
    // d_in[2], d_in[3] (images) are dead code in the reference — unused.

    float* out = (float*)d_out;
    float* Ysel_out = out + 1;          // output 1: Y_sel [1,D,N]
    float* Xf_out   = out + 1 + DN;     // output 2: Xf   [1,D,N]  (exact fp32)

    // Workspace (~29.6 MB)
    unsigned short* XH = (unsigned short*)d_ws;   // DN halves each
    unsigned short* XL = XH + DN;
    unsigned short* YH = XL + DN;
    unsigned short* YL = YH + DN;
    float* pmax = (float*)(YL + DN);                    // 2*NT*NP
    int*   pidx = (int*)(pmax + (size_t)2 * NT * NP);   // 2*NT*NP
    int*   nn   = pidx + (size_t)2 * NT * NP;           // NP
    float* inv  = (float*)(nn + NP);                    // 2*NP
    float* lacc = inv + 2 * NP;                         // 1

    hipLaunchKernelGGL(knormA, dim3(2 * NP / 256), dim3(256), 0, stream,
                       X, Y, inv, lacc);
    hipLaunchKernelGGL(knormB, dim3(NP / 64, 2), dim3(256), 0, stream,
                       X, Y, inv, Xf_out, XH, XL, YH, YL);
    hipLaunchKernelGGL(ksim, dim3(NT, NT), dim3(256), 0, stream,
                       XH, XL, YH, YL, pmax, pidx);
    hipLaunchKernelGGL(kred, dim3(NP / 256), dim3(256), 0, stream,
                       pmax, pidx, nn);
    hipLaunchKernelGGL(kgather, dim3(NP / 64, DC / 64), dim3(256), 0, stream,
                       YH, YL, nn, Xf_out, Ysel_out, lacc);
    hipLaunchKernelGGL(kfin, dim3(1), dim3(1), 0, stream, lacc, out);
}

// Round 7
// 275.330 us; speedup vs baseline: 4.8034x; 1.2253x over previous
//
#include <hip/hip_runtime.h>
#include <math.h>

// Problem constants (B=1 fixed by reference)
#define NP 9216          // S*S spatial positions
#define DC 256           // channels
#define DN (DC * NP)
#define NT 72            // 9216 / 128 tiles per dim

#define FEPS 2.220446049250313e-16f

typedef __attribute__((ext_vector_type(8))) _Float16 half8v;
typedef __attribute__((ext_vector_type(4))) float   float4v;

// async global->LDS, 16B/lane, no VGPR round-trip. LDS dest must be
// wave-uniform base + lane*16 (m104/m108) — all staging maps are flat tid*16.
__device__ __forceinline__ void gload16(const void* g, void* l)
{
    __builtin_amdgcn_global_load_lds(
        (const __attribute__((address_space(1))) unsigned int*)g,
        (__attribute__((address_space(3))) unsigned int*)l,
        16, 0, 0);
}

union HU { _Float16 h; unsigned short u; };
__device__ __forceinline__ unsigned short f2h(float f) { HU x; x.h = (_Float16)f; return x.u; }
__device__ __forceinline__ float h2f(unsigned short s) { HU x; x.u = s; return (float)x.h; }

// ---------------- Kernel 1: fused normalize + fp16 split (R7) -------------
// Replaces R6's knormA+knormB: inputs read ONCE into an LDS tile
// (64 n x 256 d fp32, row stride 257 -> conflict-free transpose), norms
// computed from LDS, all outputs written coalesced. Grid (144,2) = 288
// blocks (vs 72-block latency-bound knormA).
// Split: H = fp16(v*2^8); L = fp16((v*2^8 - H)*2^11) (exact residual).
__global__ __launch_bounds__(256) void kprep(
    const float* __restrict__ X, const float* __restrict__ Y,
    float* __restrict__ Xf_out,
    unsigned short* __restrict__ XH, unsigned short* __restrict__ XL,
    unsigned short* __restrict__ YH, unsigned short* __restrict__ YL,
    float* __restrict__ lacc)
{
    __shared__ float tile[64 * 257];   // (n, d) at n*257+d — bank (n+d)%32
    __shared__ float psum[4][64];
    __shared__ float invs[64];

    const int t = threadIdx.x;
    const bool isX = (blockIdx.y == 0);
    const float* src = isX ? X : Y;
    unsigned* hT = (unsigned*)(isX ? XH : YH);
    unsigned* lT = (unsigned*)(isX ? XL : YL);
    const int n0 = blockIdx.x * 64;

    if (blockIdx.x == 0 && blockIdx.y == 0 && t == 0) *lacc = 0.0f;

    const int lane = t & 63;
    const int w    = t >> 6;      // wave id -> owns d-range [w*64, w*64+64)

    // load phase: coalesced 256B global reads, conflict-free LDS writes
    #pragma unroll 8
    for (int i = 0; i < 64; ++i) {
        int d = w * 64 + i;
        tile[lane * 257 + d] = src[(size_t)d * NP + n0 + lane];
    }
    // norm partial over own d-range (wave-coherent, no barrier needed)
    float s = 0.0f;
    #pragma unroll 8
    for (int i = 0; i < 64; ++i) {
        float v = tile[lane * 257 + w * 64 + i];
        s = fmaf(v, v, s);
    }
    psum[w][lane] = s;
    __syncthreads();
    if (t < 64) {
        float tot = psum[0][t] + psum[1][t] + psum[2][t] + psum[3][t];
        invs[t] = 1.0f / (sqrtf(tot) + FEPS);
    }
    __syncthreads();

    // plane-write phase: thread t covers row n=t>>2, 64 d's (part=t&3).
    // Global writes fully coalesced (consecutive uints across the wave).
    {
        const int n = t >> 2;
        const int part = t & 3;
        const float inv = invs[n];
        const size_t rowb = (size_t)(n0 + n) * 128 + part * 32;
        #pragma unroll 8
        for (int j = 0; j < 32; ++j) {
            int d = part * 64 + 2 * j;
            float v0 = tile[n * 257 + d] * inv;
            float v1 = tile[n * 257 + d + 1] * inv;
            float s0 = v0 * 256.0f, s1 = v1 * 256.0f;
            unsigned short h0 = f2h(s0), h1 = f2h(s1);
            unsigned short l0 = f2h((s0 - h2f(h0)) * 2048.0f);
            unsigned short l1 = f2h((s1 - h2f(h1)) * 2048.0f);
            hT[rowb + j] = (unsigned)h0 | ((unsigned)h1 << 16);
            lT[rowb + j] = (unsigned)l0 | ((unsigned)l1 << 16);
        }
    }

    // exact fp32 Xf output ([d][n], coalesced over n)
    if (isX) {
        const float inv = invs[lane];
        #pragma unroll 8
        for (int i = 0; i < 64; ++i) {
            int d = w * 64 + i;
            Xf_out[(size_t)d * NP + n0 + lane] = tile[lane * 257 + d] * inv;
        }
    }
}

// ---------------- Kernel 2: MFMA sim-GEMM + fused per-row argmax ----------
// 128x128 tile/block, BK=32, 4 waves (2x2 of 64x64), 16x16x32 f16 MFMA.
// sim*2^16 = Hx·Hy + 2^-11(Hx·Ly + Lx·Hy) — dual accumulators, folded once.
// LDS double-buffer (2x32 KB), ONE barrier/kt. R7: col-halves combined
// in-block via LDS -> 72 partial slots (was 144), halving partial traffic.
__global__ __launch_bounds__(256, 2) void ksim(
    const unsigned short* __restrict__ XH, const unsigned short* __restrict__ XL,
    const unsigned short* __restrict__ YH, const unsigned short* __restrict__ YL,
    float* __restrict__ pmax, int* __restrict__ pidx)
{
    __shared__ unsigned short LB[2 * 16384];   // 2 buffers x 32 KB

    const int t  = threadIdx.x;
    const int n0 = blockIdx.x * 128;
    const int m0 = blockIdx.y * 128;

    // staging maps: 8 half-plane chunks/thread, flat LDS slot = tid*16B
    const int mA = t >> 2;
    const int qA = (t & 3) ^ ((mA >> 1) & 3);
    const size_t oLo = (size_t)mA * DC + qA * 8;
    const size_t oHi = (size_t)(mA + 64) * DC + qA * 8;

    const unsigned short* g0 = XH + (size_t)n0 * DC + oLo;
    const unsigned short* g1 = XH + (size_t)n0 * DC + oHi;
    const unsigned short* g2 = XL + (size_t)n0 * DC + oLo;
    const unsigned short* g3 = XL + (size_t)n0 * DC + oHi;
    const unsigned short* g4 = YH + (size_t)m0 * DC + oLo;
    const unsigned short* g5 = YH + (size_t)m0 * DC + oHi;
    const unsigned short* g6 = YL + (size_t)m0 * DC + oLo;
    const unsigned short* g7 = YL + (size_t)m0 * DC + oHi;

    char* lb = (char*)LB;
    char* const d0 = lb + 0 * 4096 + t * 16;
    char* const d1 = lb + 1 * 4096 + t * 16;
    char* const d2 = lb + 2 * 4096 + t * 16;
    char* const d3 = lb + 3 * 4096 + t * 16;
    char* const d4 = lb + 4 * 4096 + t * 16;
    char* const d5 = lb + 5 * 4096 + t * 16;
    char* const d6 = lb + 6 * 4096 + t * 16;
    char* const d7 = lb + 7 * 4096 + t * 16;

    // compute-lane maps
    const int L   = t & 63;
    const int wid = t >> 6;
    const int wnb = (wid >> 1) * 64;   // wave n-offset
    const int wmb = (wid & 1) * 64;    // wave m-offset (col half)
    const int lc  = L & 15;
    const int lq  = L >> 4;

    const int mAr = wnb + lc;
    const int cA0 = mAr * 4 + (lq ^ ((mAr >> 1) & 3));
    const int mBr = wmb + lc;
    const int cB0 = mBr * 4 + (lq ^ ((mBr >> 1) & 3));

    const char* aAh = lb + cA0 * 16;            // Ah plane at 0
    const char* aAl = aAh + 8192;               // Al
    const char* aBh = lb + 16384 + cB0 * 16;    // Bh
    const char* aBl = aBh + 8192;               // Bl

    float4v accH[4][4], accC[4][4];
    #pragma unroll
    for (int i = 0; i < 4; ++i)
        #pragma unroll
        for (int j = 0; j < 4; ++j) {
            accH[i][j] = (float4v){0.f, 0.f, 0.f, 0.f};
            accC[i][j] = (float4v){0.f, 0.f, 0.f, 0.f};
        }

    // prologue: stage kt=0 into buffer 0
    gload16(g0, d0); gload16(g1, d1); gload16(g2, d2); gload16(g3, d3);
    gload16(g4, d4); gload16(g5, d5); gload16(g6, d6); gload16(g7, d7);
    g0 += 32; g1 += 32; g2 += 32; g3 += 32;
    g4 += 32; g5 += 32; g6 += 32; g7 += 32;

    int buf = 0;
    for (int kt = 0; kt < DC / 32; ++kt) {
        // drains vmcnt (loads into `buf` done) + all waves done with the
        // other buffer -> safe to overwrite it below.
        __syncthreads();

        if (kt < DC / 32 - 1) {
            const int bo = (buf ^ 1) * 32768;
            gload16(g0, d0 + bo); gload16(g1, d1 + bo);
            gload16(g2, d2 + bo); gload16(g3, d3 + bo);
            gload16(g4, d4 + bo); gload16(g5, d5 + bo);
            gload16(g6, d6 + bo); gload16(g7, d7 + bo);
            g0 += 32; g1 += 32; g2 += 32; g3 += 32;
            g4 += 32; g5 += 32; g6 += 32; g7 += 32;
        }

        const int bo = buf * 32768;
        half8v Ah[4], Al[4];
        #pragma unroll
        for (int rb = 0; rb < 4; ++rb) {
            Ah[rb] = *(const half8v*)(aAh + bo + rb * 1024);
            Al[rb] = *(const half8v*)(aAl + bo + rb * 1024);
        }
        #pragma unroll
        for (int cb = 0; cb < 4; ++cb) {
            const half8v Bh = *(const half8v*)(aBh + bo + cb * 1024);
            const half8v Bl = *(const half8v*)(aBl + bo + cb * 1024);
            #pragma unroll
            for (int rb = 0; rb < 4; ++rb) {
                accC[rb][cb] = __builtin_amdgcn_mfma_f32_16x16x32_f16(Al[rb], Bh, accC[rb][cb], 0, 0, 0);
                accC[rb][cb] = __builtin_amdgcn_mfma_f32_16x16x32_f16(Ah[rb], Bl, accC[rb][cb], 0, 0, 0);
                accH[rb][cb] = __builtin_amdgcn_mfma_f32_16x16x32_f16(Ah[rb], Bh, accH[rb][cb], 0, 0, 0);
            }
        }
        buf ^= 1;
    }

    // ---- epilogue: fold cross term once; per-row argmax over own half ----
    // C/D map: col=lane&15, row=lq*4+reg. Scale 2^16 is argmax-invariant.
    const float CS = 1.0f / 2048.0f;
    float bv[16]; int bc[16];
    #pragma unroll
    for (int s = 0; s < 16; ++s) { bv[s] = -INFINITY; bc[s] = 0; }

    #pragma unroll
    for (int rb = 0; rb < 4; ++rb)
        #pragma unroll
        for (int cb = 0; cb < 4; ++cb) {   // cb ascending = col ascending
            const int col = m0 + wmb + cb * 16 + lc;
            #pragma unroll
            for (int r = 0; r < 4; ++r) {
                float v = fmaf(accC[rb][cb][r], CS, accH[rb][cb][r]);
                int s = rb * 4 + r;
                if (v > bv[s]) { bv[s] = v; bc[s] = col; }
            }
        }

    // reduce across the 16 lc lanes (xor<16 stays in the quad-group)
    #pragma unroll
    for (int off = 1; off < 16; off <<= 1) {
        #pragma unroll
        for (int s = 0; s < 16; ++s) {
            float ov = __shfl_xor(bv[s], off, 64);
            int   oi = __shfl_xor(bc[s], off, 64);
            if (ov > bv[s] || (ov == bv[s] && oi < bc[s])) { bv[s] = ov; bc[s] = oi; }
        }
    }

    // combine the two column-halves in-block via LDS -> one slot per tile.
    // val2[half][row-local 0..127]; half0 cols < half1 cols, so tie keeps
    // half0 (first-max, jnp.argmax semantics).
    {
        float* v2 = (float*)lb;            // 2*128 floats
        int*   i2 = (int*)(lb + 1024);     // 2*128 ints
        __syncthreads();                   // all compute reads of LDS done
        if (lc == 0) {
            const int half = wid & 1;
            #pragma unroll
            for (int rb = 0; rb < 4; ++rb)
                #pragma unroll
                for (int r = 0; r < 4; ++r) {
                    int rl = wnb + rb * 16 + lq * 4 + r;
                    v2[half * 128 + rl] = bv[rb * 4 + r];
                    i2[half * 128 + rl] = bc[rb * 4 + r];
                }
        }
        __syncthreads();
        if (t < 128) {
            float va = v2[t], vb = v2[128 + t];
            int   ia = i2[t], ib = i2[128 + t];
            bool useB = vb > va;
            pmax[(size_t)blockIdx.y * NP + n0 + t] = useB ? vb : va;
            pidx[(size_t)blockIdx.y * NP + n0 + t] = useB ? ib : ia;
        }
    }
}

// ---------------- Kernel 3: reduce 72 tile partials -> nn_idx -------------
// 144 blocks x 256 threads: 4 threads/row scan 18 slots each, LDS combine.
__global__ __launch_bounds__(256) void kred(
    const float* __restrict__ pmax, const int* __restrict__ pidx,
    int* __restrict__ nn)
{
    __shared__ float cv[4][64];
    __shared__ int   ci[4][64];

    const int t = threadIdx.x;
    const int n = blockIdx.x * 64 + (t & 63);
    const int p = t >> 6;

    float b = -INFINITY;
    int bi = 0x7fffffff;
    #pragma unroll 6
    for (int c = p * 18; c < p * 18 + 18; ++c) {
        float v = pmax[(size_t)c * NP + n];
        int  id = pidx[(size_t)c * NP + n];
        if (v > b || (v == b && id < bi)) { b = v; bi = id; }
    }
    cv[p][t & 63] = b;
    ci[p][t & 63] = bi;
    __syncthreads();
    if (t < 64) {
        b = cv[0][t]; bi = ci[0][t];
        #pragma unroll
        for (int q = 1; q < 4; ++q) {
            float v = cv[q][t]; int id = ci[q][t];
            if (v > b || (v == b && id < bi)) { b = v; bi = id; }
        }
        nn[blockIdx.x * 64 + t] = bi;
    }
}

// ---------------- Kernel 4: gather Y_sel + fused MSE loss ----------------
// y = H*2^-8 + L*2^-19 (<=6e-8 from exact fp32).
__global__ __launch_bounds__(256) void kgather(
    const unsigned short* __restrict__ YH, const unsigned short* __restrict__ YL,
    const int* __restrict__ nn,
    const float* __restrict__ Xf, float* __restrict__ Ysel,
    float* __restrict__ lacc)
{
    __shared__ float tile[64][65];
    __shared__ int   idxs[64];
    __shared__ float wsum[4];

    const int n0 = blockIdx.x * 64;
    const int d0 = blockIdx.y * 64;
    const int tid = threadIdx.x;

    if (tid < 64) idxs[tid] = nn[n0 + tid];
    __syncthreads();

    const int c  = tid & 63;
    const int r0 = tid >> 6;

    #pragma unroll
    for (int s = 0; s < 16; ++s) {
        int r = s * 4 + r0;
        long base = (long)idxs[r] * DC + d0 + c;
        tile[r][c] = h2f(YH[base]) * (1.0f / 256.0f)
                   + h2f(YL[base]) * (1.0f / 524288.0f);   // 2^-19
    }
    __syncthreads();

    float lsum = 0.0f;
    #pragma unroll
    for (int s = 0; s < 16; ++s) {
        int a = s * 4 + r0;
        int d = d0 + a;
        int n = n0 + c;
        float y = tile[c][a];          // stride-65: conflict-free
        float x = Xf[(long)d * NP + n];
        float diff = x - y;
        lsum = fmaf(diff, diff, lsum);
        Ysel[(long)d * NP + n] = y;    // coalesced over n
    }

    #pragma unroll
    for (int off = 32; off >= 1; off >>= 1)
        lsum += __shfl_xor(lsum, off, 64);
    if ((tid & 63) == 0) wsum[tid >> 6] = lsum;
    __syncthreads();
    if (tid == 0)
        atomicAdd(lacc, wsum[0] + wsum[1] + wsum[2] + wsum[3]);
}

// ---------------- Kernel 5: finalize loss ----------------
__global__ void kfin(const float* __restrict__ lacc, float* __restrict__ out)
{
    out[0] = lacc[0] * (1.0f / (float)DN);
}

extern "C" void kernel_launch(void* const* d_in, const int* in_sizes, int n_in,
                              void* d_out, int out_size, void* d_ws, size_t ws_size,
                              hipStream_t stream)
{
    const float* X = (const float*)d_in[0];   // X_features [1,256,96,96]
    const float* Y = (const float*)d_in[1];   // Y_features [1,256,96,96]
    // d_in[2], d_in[3] (images) are dead code in the reference — unused.

    float* out = (float*)d_out;
    float* Ysel_out = out + 1;          // output 1: Y_sel [1,D,N]
    float* Xf_out   = out + 1 + DN;     // output 2: Xf   [1,D,N]  (exact fp32)

    // Workspace (~24.3 MB)
    unsigned short* XH = (unsigned short*)d_ws;   // DN halves each
    unsigned short* XL = XH + DN;
    unsigned short* YH = XL + DN;
    unsigned short* YL = YH + DN;
    float* pmax = (float*)(YL + DN);                // NT*NP
    int*   pidx = (int*)(pmax + (size_t)NT * NP);   // NT*NP
    int*   nn   = pidx + (size_t)NT * NP;           // NP
    float* lacc = (float*)(nn + NP);                // 1

    hipLaunchKernelGGL(kprep, dim3(NP / 64, 2), dim3(256), 0, stream,
                       X, Y, Xf_out, XH, XL, YH, YL, lacc);
    hipLaunchKernelGGL(ksim, dim3(NT, NT), dim3(256), 0, stream,
                       XH, XL, YH, YL, pmax, pidx);
    hipLaunchKernelGGL(kred, dim3(NP / 64), dim3(256), 0, stream,
                       pmax, pidx, nn);
    hipLaunchKernelGGL(kgather, dim3(NP / 64, DC / 64), dim3(256), 0, stream,
                       YH, YL, nn, Xf_out, Ysel_out, lacc);
    hipLaunchKernelGGL(kfin, dim3(1), dim3(1), 0, stream, lacc, out);
}

// Round 8
// 268.472 us; speedup vs baseline: 4.9261x; 1.0255x over previous
//
#include <hip/hip_runtime.h>
#include <math.h>

// Problem constants (B=1 fixed by reference)
#define NP 9216          // S*S spatial positions
#define DC 256           // channels
#define DN (DC * NP)
#define NT 72            // 9216 / 128 tiles per dim
#define KCH (NP * 32)    // halves per k-chunk section of a plane

#define FEPS 2.220446049250313e-16f

typedef __attribute__((ext_vector_type(8))) _Float16 half8v;
typedef __attribute__((ext_vector_type(4))) float   float4v;

union HU { _Float16 h; unsigned short u; };
__device__ __forceinline__ unsigned short f2h(float f) { HU x; x.h = (_Float16)f; return x.u; }
__device__ __forceinline__ float h2f(unsigned short s) { HU x; x.u = s; return (float)x.h; }

// Plane layout (R8, k-major): half index off(n,k) =
//   (k>>5)*KCH + n*32 + (k&31)
// so one MFMA fragment load (16 positions x 64B) is 1KB contiguous ->
// perfectly coalesced global_load_dwordx4 straight from L2. This is what
// lets ksim run with NO LDS staging and NO barriers in the K-loop.

// ---------------- Kernel 1: fused normalize + fp16 split ----------------
// Inputs read once into an LDS tile (64n x 256d fp32, stride 257), norms
// from LDS, outputs written coalesced in the k-major plane layout.
// Split: H = fp16(v*2^8); L = fp16((v*2^8 - H)*2^11) (exact residual).
__global__ __launch_bounds__(256) void kprep(
    const float* __restrict__ X, const float* __restrict__ Y,
    float* __restrict__ Xf_out,
    unsigned short* __restrict__ XH, unsigned short* __restrict__ XL,
    unsigned short* __restrict__ YH, unsigned short* __restrict__ YL,
    float* __restrict__ lacc)
{
    __shared__ float tile[64 * 257];   // (n, d) at n*257+d
    __shared__ float psum[4][64];
    __shared__ float invs[64];

    const int t = threadIdx.x;
    const bool isX = (blockIdx.y == 0);
    const float* src = isX ? X : Y;
    unsigned* hT = (unsigned*)(isX ? XH : YH);
    unsigned* lT = (unsigned*)(isX ? XL : YL);
    const int n0 = blockIdx.x * 64;

    if (blockIdx.x == 0 && blockIdx.y == 0 && t == 0) *lacc = 0.0f;

    const int lane = t & 63;
    const int w    = t >> 6;      // wave id -> owns d-range [w*64, w*64+64)

    #pragma unroll 8
    for (int i = 0; i < 64; ++i) {
        int d = w * 64 + i;
        tile[lane * 257 + d] = src[(size_t)d * NP + n0 + lane];
    }
    float s = 0.0f;
    #pragma unroll 8
    for (int i = 0; i < 64; ++i) {
        float v = tile[lane * 257 + w * 64 + i];
        s = fmaf(v, v, s);
    }
    psum[w][lane] = s;
    __syncthreads();
    if (t < 64) {
        float tot = psum[0][t] + psum[1][t] + psum[2][t] + psum[3][t];
        invs[t] = 1.0f / (sqrtf(tot) + FEPS);
    }
    __syncthreads();

    // plane writes, k-major layout; consecutive threads -> consecutive
    // uints (coalesced). 8 k-chunks x 4 passes x (16n x 16u).
    for (int kt = 0; kt < 8; ++kt) {
        #pragma unroll
        for (int p = 0; p < 4; ++p) {
            int idx = p * 256 + t;
            int n = idx >> 4;          // 0..63
            int u = idx & 15;          // uint within chunk (2 halves)
            float inv = invs[n];
            int d = kt * 32 + 2 * u;
            float v0 = tile[n * 257 + d] * inv;
            float v1 = tile[n * 257 + d + 1] * inv;
            float s0 = v0 * 256.0f, s1 = v1 * 256.0f;
            unsigned short h0 = f2h(s0), h1 = f2h(s1);
            unsigned short l0 = f2h((s0 - h2f(h0)) * 2048.0f);
            unsigned short l1 = f2h((s1 - h2f(h1)) * 2048.0f);
            size_t uo = (size_t)kt * (NP * 16) + (size_t)(n0 + n) * 16 + u;
            hT[uo] = (unsigned)h0 | ((unsigned)h1 << 16);
            lT[uo] = (unsigned)l0 | ((unsigned)l1 << 16);
        }
    }

    // exact fp32 Xf output ([d][n], coalesced over n)
    if (isX) {
        const float inv = invs[lane];
        #pragma unroll 8
        for (int i = 0; i < 64; ++i) {
            int d = w * 64 + i;
            Xf_out[(size_t)d * NP + n0 + lane] = tile[lane * 257 + d] * inv;
        }
    }
}

// ---------------- Kernel 2: MFMA sim-GEMM + fused per-row argmax ----------
// R8: barrier-free K-loop. 128x128 tile/block, 4 waves (2x2 of 64x64),
// 16x16x32 f16 MFMA. Fragments loaded DIRECTLY from global (k-major
// layout -> 1KB contiguous per instruction, L2-resident planes). No LDS
// staging, no __syncthreads until the epilogue. Single accumulator +
// per-kt cross-term fold keeps VGPR ~150 -> 3 waves/SIMD.
// sim*2^16 = Hx·Hy + 2^-11(Hx·Ly + Lx·Hy).
__global__ __launch_bounds__(256, 3) void ksim(
    const unsigned short* __restrict__ XH, const unsigned short* __restrict__ XL,
    const unsigned short* __restrict__ YH, const unsigned short* __restrict__ YL,
    float* __restrict__ pmax, int* __restrict__ pidx)
{
    __shared__ float v2s[256];
    __shared__ int   i2s[256];

    const int t  = threadIdx.x;
    const int n0 = blockIdx.x * 128;
    const int m0 = blockIdx.y * 128;

    const int L   = t & 63;
    const int wid = t >> 6;
    const int wnb = (wid >> 1) * 64;   // wave n-offset
    const int wmb = (wid & 1) * 64;    // wave m-offset (col half)
    const int lc  = L & 15;
    const int lq  = L >> 4;

    // fragment base pointers (halves); rb/cb handled via inst offsets
    // (i*512 halves = 1024B <= 13-bit imm). A-frag: row = n, k = lq*8+j.
    const unsigned short* pAh = XH + (size_t)(n0 + wnb + lc) * 32 + lq * 8;
    const unsigned short* pAl = XL + (size_t)(n0 + wnb + lc) * 32 + lq * 8;
    const unsigned short* pBh = YH + (size_t)(m0 + wmb + lc) * 32 + lq * 8;
    const unsigned short* pBl = YL + (size_t)(m0 + wmb + lc) * 32 + lq * 8;

    float4v acc[4][4];
    #pragma unroll
    for (int i = 0; i < 4; ++i)
        #pragma unroll
        for (int j = 0; j < 4; ++j)
            acc[i][j] = (float4v){0.f, 0.f, 0.f, 0.f};
    const float4v z4 = (float4v){0.f, 0.f, 0.f, 0.f};
    const float CS = 1.0f / 2048.0f;

    #pragma unroll 1
    for (int kt = 0; kt < 8; ++kt) {
        half8v Ah[4], Al[4], Bh[4], Bl[4];
        #pragma unroll
        for (int i = 0; i < 4; ++i) {
            Ah[i] = *(const half8v*)(pAh + i * 512);
            Al[i] = *(const half8v*)(pAl + i * 512);
            Bh[i] = *(const half8v*)(pBh + i * 512);
            Bl[i] = *(const half8v*)(pBl + i * 512);
        }
        #pragma unroll
        for (int cb = 0; cb < 4; ++cb)
            #pragma unroll
            for (int rb = 0; rb < 4; ++rb) {
                float4v tv;
                tv = __builtin_amdgcn_mfma_f32_16x16x32_f16(Al[rb], Bh[cb], z4, 0, 0, 0);
                tv = __builtin_amdgcn_mfma_f32_16x16x32_f16(Ah[rb], Bl[cb], tv, 0, 0, 0);
                acc[rb][cb] = __builtin_amdgcn_mfma_f32_16x16x32_f16(Ah[rb], Bh[cb], acc[rb][cb], 0, 0, 0);
                acc[rb][cb].x = fmaf(tv.x, CS, acc[rb][cb].x);
                acc[rb][cb].y = fmaf(tv.y, CS, acc[rb][cb].y);
                acc[rb][cb].z = fmaf(tv.z, CS, acc[rb][cb].z);
                acc[rb][cb].w = fmaf(tv.w, CS, acc[rb][cb].w);
            }
        pAh += KCH; pAl += KCH; pBh += KCH; pBl += KCH;
    }

    // ---- epilogue: per-row argmax over own col-half ----
    // C/D map: col=lane&15, row=lq*4+reg. Scale 2^16 is argmax-invariant.
    float bv[16]; int bc[16];
    #pragma unroll
    for (int s = 0; s < 16; ++s) { bv[s] = -INFINITY; bc[s] = 0; }

    #pragma unroll
    for (int rb = 0; rb < 4; ++rb)
        #pragma unroll
        for (int cb = 0; cb < 4; ++cb) {   // cb ascending = col ascending
            const int col = m0 + wmb + cb * 16 + lc;
            #pragma unroll
            for (int r = 0; r < 4; ++r) {
                float v = acc[rb][cb][r];
                int s = rb * 4 + r;
                if (v > bv[s]) { bv[s] = v; bc[s] = col; }
            }
        }

    // reduce across the 16 lc lanes (xor<16 stays in the quad-group)
    #pragma unroll
    for (int off = 1; off < 16; off <<= 1) {
        #pragma unroll
        for (int s = 0; s < 16; ++s) {
            float ov = __shfl_xor(bv[s], off, 64);
            int   oi = __shfl_xor(bc[s], off, 64);
            if (ov > bv[s] || (ov == bv[s] && oi < bc[s])) { bv[s] = ov; bc[s] = oi; }
        }
    }

    // combine the two column-halves via LDS -> one slot per tile.
    // half0 cols < half1 cols, so strict '>' keeps half0 on ties
    // (jnp.argmax first-max semantics).
    if (lc == 0) {
        const int half = wid & 1;
        #pragma unroll
        for (int rb = 0; rb < 4; ++rb)
            #pragma unroll
            for (int r = 0; r < 4; ++r) {
                int rl = wnb + rb * 16 + lq * 4 + r;
                v2s[half * 128 + rl] = bv[rb * 4 + r];
                i2s[half * 128 + rl] = bc[rb * 4 + r];
            }
    }
    __syncthreads();
    if (t < 128) {
        float va = v2s[t], vb = v2s[128 + t];
        int   ia = i2s[t], ib = i2s[128 + t];
        bool useB = vb > va;
        pmax[(size_t)blockIdx.y * NP + n0 + t] = useB ? vb : va;
        pidx[(size_t)blockIdx.y * NP + n0 + t] = useB ? ib : ia;
    }
}

// ---------------- Kernel 3: reduce 72 tile partials -> nn_idx -------------
// 144 blocks x 256 threads: 4 threads/row scan 18 slots each, LDS combine.
__global__ __launch_bounds__(256) void kred(
    const float* __restrict__ pmax, const int* __restrict__ pidx,
    int* __restrict__ nn)
{
    __shared__ float cv[4][64];
    __shared__ int   ci[4][64];

    const int t = threadIdx.x;
    const int n = blockIdx.x * 64 + (t & 63);
    const int p = t >> 6;

    float b = -INFINITY;
    int bi = 0x7fffffff;
    #pragma unroll 6
    for (int c = p * 18; c < p * 18 + 18; ++c) {
        float v = pmax[(size_t)c * NP + n];
        int  id = pidx[(size_t)c * NP + n];
        if (v > b || (v == b && id < bi)) { b = v; bi = id; }
    }
    cv[p][t & 63] = b;
    ci[p][t & 63] = bi;
    __syncthreads();
    if (t < 64) {
        b = cv[0][t]; bi = ci[0][t];
        #pragma unroll
        for (int q = 1; q < 4; ++q) {
            float v = cv[q][t]; int id = ci[q][t];
            if (v > b || (v == b && id < bi)) { b = v; bi = id; }
        }
        nn[blockIdx.x * 64 + t] = bi;
    }
}

// ---------------- Kernel 4: gather Y_sel + fused MSE loss ----------------
// y = H*2^-8 + L*2^-19 (<=6e-8 from exact fp32). k-major plane layout:
// row n's halves for d in [d0,d0+64) live in 2 chunks of 32 -> two 64B
// segments per row, coalesced across the 64 c-lanes.
__global__ __launch_bounds__(256) void kgather(
    const unsigned short* __restrict__ YH, const unsigned short* __restrict__ YL,
    const int* __restrict__ nn,
    const float* __restrict__ Xf, float* __restrict__ Ysel,
    float* __restrict__ lacc)
{
    __shared__ float tile[64][65];
    __shared__ int   idxs[64];
    __shared__ float wsum[4];

    const int n0 = blockIdx.x * 64;
    const int d0 = blockIdx.y * 64;
    const int tid = threadIdx.x;

    if (tid < 64) idxs[tid] = nn[n0 + tid];
    __syncthreads();

    const int c  = tid & 63;
    const int r0 = tid >> 6;

    #pragma unroll
    for (int s = 0; s < 16; ++s) {
        int r = s * 4 + r0;
        int d = d0 + c;
        size_t off = (size_t)(d >> 5) * KCH + (size_t)idxs[r] * 32 + (d & 31);
        tile[r][c] = h2f(YH[off]) * (1.0f / 256.0f)
                   + h2f(YL[off]) * (1.0f / 524288.0f);   // 2^-19
    }
    __syncthreads();

    float lsum = 0.0f;
    #pragma unroll
    for (int s = 0; s < 16; ++s) {
        int a = s * 4 + r0;
        int d = d0 + a;
        int n = n0 + c;
        float y = tile[c][a];          // stride-65: conflict-free
        float x = Xf[(size_t)d * NP + n];
        float diff = x - y;
        lsum = fmaf(diff, diff, lsum);
        Ysel[(size_t)d * NP + n] = y;  // coalesced over n
    }

    #pragma unroll
    for (int off = 32; off >= 1; off >>= 1)
        lsum += __shfl_xor(lsum, off, 64);
    if ((tid & 63) == 0) wsum[tid >> 6] = lsum;
    __syncthreads();
    if (tid == 0)
        atomicAdd(lacc, wsum[0] + wsum[1] + wsum[2] + wsum[3]);
}

// ---------------- Kernel 5: finalize loss ----------------
__global__ void kfin(const float* __restrict__ lacc, float* __restrict__ out)
{
    out[0] = lacc[0] * (1.0f / (float)DN);
}

extern "C" void kernel_launch(void* const* d_in, const int* in_sizes, int n_in,
                              void* d_out, int out_size, void* d_ws, size_t ws_size,
                              hipStream_t stream)
{
    const float* X = (const float*)d_in[0];   // X_features [1,256,96,96]
    const float* Y = (const float*)d_in[1];   // Y_features [1,256,96,96]
    // d_in[2], d_in[3] (images) are dead code in the reference — unused.

    float* out = (float*)d_out;
    float* Ysel_out = out + 1;          // output 1: Y_sel [1,D,N]
    float* Xf_out   = out + 1 + DN;     // output 2: Xf   [1,D,N]  (exact fp32)

    // Workspace (~24.3 MB)
    unsigned short* XH = (unsigned short*)d_ws;   // DN halves each
    unsigned short* XL = XH + DN;
    unsigned short* YH = XL + DN;
    unsigned short* YL = YH + DN;
    float* pmax = (float*)(YL + DN);                // NT*NP
    int*   pidx = (int*)(pmax + (size_t)NT * NP);   // NT*NP
    int*   nn   = pidx + (size_t)NT * NP;           // NP
    float* lacc = (float*)(nn + NP);                // 1

    hipLaunchKernelGGL(kprep, dim3(NP / 64, 2), dim3(256), 0, stream,
                       X, Y, Xf_out, XH, XL, YH, YL, lacc);
    hipLaunchKernelGGL(ksim, dim3(NT, NT), dim3(256), 0, stream,
                       XH, XL, YH, YL, pmax, pidx);
    hipLaunchKernelGGL(kred, dim3(NP / 64), dim3(256), 0, stream,
                       pmax, pidx, nn);
    hipLaunchKernelGGL(kgather, dim3(NP / 64, DC / 64), dim3(256), 0, stream,
                       YH, YL, nn, Xf_out, Ysel_out, lacc);
    hipLaunchKernelGGL(kfin, dim3(1), dim3(1), 0, stream, lacc, out);
}